// Round 3
// baseline (218.090 us; speedup 1.0000x reference)
//
#include <hip/hip_runtime.h>
#include <hip/hip_bf16.h>

#define B_   2
#define T_   2048
#define C_   1024
#define H_   16
#define KV_  4
#define HD_  64
#define M_   (B_*T_)     // 4096 tokens
#define NQKV_ 1536       // 1024 q + 256 k + 256 v (v region unused now)
#define M8L2E_ 11.5415603f   // 8 * log2(e)

typedef __bf16 bf16x8 __attribute__((ext_vector_type(8)));
typedef float  f32x4  __attribute__((ext_vector_type(4)));

static __device__ __forceinline__ unsigned short f2bf(float f) {
    __hip_bfloat16 h = __float2bfloat16(f);
    return __builtin_bit_cast(unsigned short, h);
}
static __device__ __forceinline__ unsigned int pk2(float a, float b) {
    return (unsigned int)f2bf(a) | ((unsigned int)f2bf(b) << 16);
}
// concat two 4-bf16 register pairs into one MFMA bf16x8 operand
static __device__ __forceinline__ bf16x8 cat8(uint2 a, uint2 b) {
    uint4 u; u.x = a.x; u.y = a.y; u.z = b.x; u.w = b.y;
    return __builtin_bit_cast(bf16x8, u);
}

// ---------------------------------------------------------------- prep: cast x + 4 weight transposes
__global__ void prep_kernel(const float* __restrict__ x, unsigned short* __restrict__ xb,
                            const float* __restrict__ Wq, const float* __restrict__ Wk,
                            const float* __restrict__ Wv, const float* __restrict__ Wo,
                            unsigned short* __restrict__ wtqkv, unsigned short* __restrict__ wto) {
    __shared__ float tile[32][33];
    int bid = blockIdx.x;
    if (bid < 4096) {   // cast x -> bf16
        int i = (bid * 256 + threadIdx.x) * 4;
        float4 v = *(const float4*)(x + i);
        ushort4 o = make_ushort4(f2bf(v.x), f2bf(v.y), f2bf(v.z), f2bf(v.w));
        *(ushort4*)(xb + i) = o;
        return;
    }
    bid -= 4096;
    const float* src; unsigned short* dst; int s, nlog;
    if (bid < 1024)      { src = Wq; dst = wtqkv;               s = bid;        nlog = 5; }
    else if (bid < 1280) { src = Wk; dst = wtqkv + 1024 * 1024; s = bid - 1024; nlog = 3; }
    else if (bid < 1536) { src = Wv; dst = wtqkv + 1280 * 1024; s = bid - 1280; nlog = 3; }
    else                 { src = Wo; dst = wto;                 s = bid - 1536; nlog = 5; }
    int N  = 32 << nlog;
    int k0 = (s >> nlog) * 32, n0 = (s & ((1 << nlog) - 1)) * 32;
    int lr = threadIdx.x >> 5, lc = threadIdx.x & 31;
    #pragma unroll
    for (int i = 0; i < 4; i++) {
        int r = lr + i * 8;
        tile[r][lc] = src[(k0 + r) * N + n0 + lc];
    }
    __syncthreads();
    #pragma unroll
    for (int i = 0; i < 4; i++) {
        int r = lr + i * 8;
        dst[(n0 + r) * 1024 + k0 + lc] = f2bf(tile[lc][r]);
    }
}

// ------------------------------------------------ 128x64 bf16 MFMA GEMM, K=1024, BK=64
// grid = (heads, m-blocks): head-major so same-A-panel blocks are temporally adjacent (L2-hot).
// ROPE=true: heads 0..15 q (RoPE+RMS, *0.125*log2e), 16..19 k (RoPE+RMS),
//            20..23 v -> written TRANSPOSED straight to vtb[(b*KV+kvh)*64+d][t].
template <typename T, bool ROPE>
__global__ __launch_bounds__(256) void gemm_kernel(const unsigned short* __restrict__ A,
                                                   const unsigned short* __restrict__ Bt,
                                                   T* __restrict__ Cm, int Ni,
                                                   const float* __restrict__ cosb,
                                                   const float* __restrict__ sinb,
                                                   unsigned short* __restrict__ vtb) {
    __shared__ __align__(16) unsigned short As[2][128 * 32];
    __shared__ __align__(16) unsigned short Bs[2][64 * 32];
    int head = blockIdx.x;
    int m0 = blockIdx.y * 128;
    int n0 = head * 64;
    int tid = threadIdx.x;
    int w = tid >> 6, lane = tid & 63;
    int col = lane & 15, quad = lane >> 4;
    int wm = w * 32;
    int ar = tid >> 2, ak = (tid & 3) * 8;

    f32x4 acc[2][4];
    #pragma unroll
    for (int mt = 0; mt < 2; mt++)
        #pragma unroll
        for (int nt = 0; nt < 4; nt++) acc[mt][nt] = (f32x4){0.f, 0.f, 0.f, 0.f};

    for (int k0 = 0; k0 < 1024; k0 += 64) {
        #pragma unroll
        for (int hh = 0; hh < 2; hh++) {
            __builtin_amdgcn_global_load_lds(
                (const __attribute__((address_space(1))) unsigned int*)(A + (size_t)(m0 + ar) * 1024 + k0 + hh * 32 + ak),
                (__attribute__((address_space(3))) unsigned int*)(&As[hh][ar * 32 + ak]), 16, 0, 0);
            __builtin_amdgcn_global_load_lds(
                (const __attribute__((address_space(1))) unsigned int*)(A + (size_t)(m0 + ar + 64) * 1024 + k0 + hh * 32 + ak),
                (__attribute__((address_space(3))) unsigned int*)(&As[hh][(ar + 64) * 32 + ak]), 16, 0, 0);
            __builtin_amdgcn_global_load_lds(
                (const __attribute__((address_space(1))) unsigned int*)(Bt + (size_t)(n0 + ar) * 1024 + k0 + hh * 32 + ak),
                (__attribute__((address_space(3))) unsigned int*)(&Bs[hh][ar * 32 + ak]), 16, 0, 0);
        }
        __syncthreads();
        bf16x8 af[2][2], bfr[4][2];
        #pragma unroll
        for (int hh = 0; hh < 2; hh++) {
            #pragma unroll
            for (int mt = 0; mt < 2; mt++) af[mt][hh]  = *(const bf16x8*)&As[hh][(wm + mt * 16 + col) * 32 + quad * 8];
            #pragma unroll
            for (int nt = 0; nt < 4; nt++) bfr[nt][hh] = *(const bf16x8*)&Bs[hh][(nt * 16 + col) * 32 + quad * 8];
        }
        #pragma unroll
        for (int hh = 0; hh < 2; hh++)
            #pragma unroll
            for (int mt = 0; mt < 2; mt++)
                #pragma unroll
                for (int nt = 0; nt < 4; nt++)
                    acc[mt][nt] = __builtin_amdgcn_mfma_f32_16x16x32_bf16(af[mt][hh], bfr[nt][hh], acc[mt][nt], 0, 0, 0);
        __syncthreads();
    }

    if constexpr (ROPE) {
        if (head >= H_ + KV_) {
            // v head: write transposed to vtb[(b*KV+kvh)*64 + d][t], packed 4x bf16 (t-contig)
            int kvh = head - (H_ + KV_);
            int b = m0 >> 11;
            #pragma unroll
            for (int mt = 0; mt < 2; mt++) {
                int tb = (m0 + wm + mt * 16 + quad * 4) & (T_ - 1);
                #pragma unroll
                for (int nt = 0; nt < 4; nt++) {
                    int d = nt * 16 + col;
                    uint2 pv;
                    pv.x = pk2(acc[mt][nt][0], acc[mt][nt][1]);
                    pv.y = pk2(acc[mt][nt][2], acc[mt][nt][3]);
                    *(uint2*)&vtb[((size_t)((b * KV_ + kvh) * 64 + d)) * T_ + tb] = pv;
                }
            }
            return;
        }
        // q/k head: RoPE + RMSNorm
        #pragma unroll
        for (int mt = 0; mt < 2; mt++)
            #pragma unroll
            for (int r = 0; r < 4; r++) {
                int t = (m0 + wm + mt * 16 + quad * 4 + r) & (T_ - 1);
                float nv[4];
                #pragma unroll
                for (int nt = 0; nt < 4; nt++) {
                    int i = (nt & 1) * 16 + col;
                    float c = cosb[t * 32 + i], s = sinb[t * 32 + i];
                    float v = acc[mt][nt][r], p = acc[mt][nt ^ 2][r];
                    nv[nt] = (nt < 2) ? (v * c + p * s) : (v * c - p * s);
                }
                float sq = nv[0] * nv[0] + nv[1] * nv[1] + nv[2] * nv[2] + nv[3] * nv[3];
                sq += __shfl_xor(sq, 1, 64);
                sq += __shfl_xor(sq, 2, 64);
                sq += __shfl_xor(sq, 4, 64);
                sq += __shfl_xor(sq, 8, 64);
                float rr = rsqrtf(sq * (1.0f / 64.0f) + 1e-6f);
                if (head < H_) rr *= 0.125f * 1.44269504f;   // attn scale * log2(e) folded into q
                #pragma unroll
                for (int nt = 0; nt < 4; nt++) acc[mt][nt][r] = nv[nt] * rr;
            }
    }

    #pragma unroll
    for (int mt = 0; mt < 2; mt++)
        #pragma unroll
        for (int nt = 0; nt < 4; nt++)
            #pragma unroll
            for (int r = 0; r < 4; r++) {
                size_t idx = (size_t)(m0 + wm + mt * 16 + quad * 4 + r) * Ni + n0 + nt * 16 + col;
                if constexpr (sizeof(T) == 2) Cm[idx] = f2bf(acc[mt][nt][r]);
                else                          Cm[idx] = acc[mt][nt][r];
            }
}

// ------------------------------------------------ MFMA flash attention: split-K, all-register P
// BALANCED PAIRING: block handles q-tile pair (63-pi, pi); 1024 identical blocks co-resident.
// NOTE: plain __launch_bounds__(256). min-waves=4 once forced VGPR to 64 -> 95 MB spill. Never re-add.
// QK^T computed TRANSPOSED (A=K, B=Q): lane holds P[q=col][key=quad*4+r] (4 consecutive keys).
// PV with NO LDS round-trip: MFMA's contraction index k is just an enumeration, so remap
// global k=quad*8+j to keys of a PAIR of 16-key blocks (j<4 -> block 2p, j>=4 -> block 2p+1).
// A operand = concat of two packed-bf16 quads (registers); B operand = concat of two b64 V
// loads at t=kt*64+m*16+quad*4. Same key(k) map both sides => exact. Removes 8 ds_write +
// 4 ds_read + 2 lgkmcnt serialization points per iter and all k-loop bank conflicts.
// Fixed-max softmax via exp2 (log2e folded into q): p = 2^(s' - 8*log2e), additive partials.
__global__ __launch_bounds__(256) void attn_kernel(const unsigned short* __restrict__ qkvb,
                                                   const unsigned short* __restrict__ vtb,
                                                   unsigned short* __restrict__ yb) {
    __shared__ __align__(16) float Obuf[4 * 32 * 64];   // 32 KB merge buffer
    __shared__ float lbuf[4][32];

    int bh = blockIdx.x & 31;
    int pi = blockIdx.x >> 5;               // pair index 0..31
    int b = bh >> 4, h = bh & 15, kvh = h >> 2;
    int tid = threadIdx.x;
    int w = tid >> 6, lane = tid & 63;
    int col = lane & 15, quad = lane >> 4;

    const unsigned short* kptr = qkvb + (size_t)(b * T_) * NQKV_ + 1024 + kvh * 64;
    const unsigned short* vptr = vtb + (size_t)((b * KV_ + kvh) * 64) * T_;

    bf16x8 ones;
    #pragma unroll
    for (int j = 0; j < 8; j++) ones[j] = (__bf16)1.0f;

    for (int ti = 0; ti < 2; ti++) {
        int qt = ti ? pi : 63 - pi;         // big tile first
        int t0 = qt * 32;
        int nkt = (t0 + 95) >> 6;           // 64-key tiles covering keys <= t0+31
        int we = ti ? 3 - w : w;            // reversed wave order on 2nd tile

        // Q B-frags (loop-invariant per tile): lane(col=q, quad) holds Q[t0+ntq*16+col][quad*8+step*32..]
        bf16x8 aq[2][2];
        #pragma unroll
        for (int ntq = 0; ntq < 2; ntq++)
            #pragma unroll
            for (int step = 0; step < 2; step++)
                aq[ntq][step] = *(const bf16x8*)&qkvb[(size_t)(b * T_ + t0 + ntq * 16 + col) * NQKV_
                                                      + h * 64 + quad * 8 + step * 32];

        f32x4 o[2][4], lacc[2];
        #pragma unroll
        for (int mt = 0; mt < 2; mt++) {
            lacc[mt] = (f32x4){0.f, 0.f, 0.f, 0.f};
            #pragma unroll
            for (int nt = 0; nt < 4; nt++) o[mt][nt] = (f32x4){0.f, 0.f, 0.f, 0.f};
        }

        for (int kt = we; kt < nkt; kt += 4) {
            // V loads first (16x b64): latency hides under QK MFMAs + exp
            // lane (col,quad) gets V[t = kt*64 + mtk*16 + quad*4 ..+3][d = ntd*16+col]
            uint2 vraw[4][4];
            #pragma unroll
            for (int mtk = 0; mtk < 4; mtk++)
                #pragma unroll
                for (int ntd = 0; ntd < 4; ntd++)
                    vraw[mtk][ntd] = *(const uint2*)&vptr[(size_t)(ntd * 16 + col) * T_
                                                          + kt * 64 + mtk * 16 + quad * 4];
            // S^T = K Q^T : A-frag = K rows (key), B-frag = Q
            f32x4 sacc[4][2];
            #pragma unroll
            for (int mtk = 0; mtk < 4; mtk++)
                #pragma unroll
                for (int ntq = 0; ntq < 2; ntq++) sacc[mtk][ntq] = (f32x4){0.f, 0.f, 0.f, 0.f};
            #pragma unroll
            for (int step = 0; step < 2; step++) {
                bf16x8 kb[4];
                #pragma unroll
                for (int mtk = 0; mtk < 4; mtk++)
                    kb[mtk] = *(const bf16x8*)&kptr[(size_t)(kt * 64 + mtk * 16 + col) * NQKV_
                                                    + quad * 8 + step * 32];
                #pragma unroll
                for (int mtk = 0; mtk < 4; mtk++)
                    #pragma unroll
                    for (int ntq = 0; ntq < 2; ntq++)
                        sacc[mtk][ntq] = __builtin_amdgcn_mfma_f32_16x16x32_bf16(kb[mtk], aq[ntq][step], sacc[mtk][ntq], 0, 0, 0);
            }
            bool diag = (kt == nkt - 1);
            // p = 2^(s' - 8*log2e), packed to bf16 pairs in registers (no LDS)
            uint2 pw[4][2];
            #pragma unroll
            for (int mtk = 0; mtk < 4; mtk++)
                #pragma unroll
                for (int ntq = 0; ntq < 2; ntq++) {
                    if (diag) {   // causal mask on the diagonal tile (row=key, col=q)
                        #pragma unroll
                        for (int r = 0; r < 4; r++)
                            if (kt * 64 + mtk * 16 + quad * 4 + r > t0 + ntq * 16 + col)
                                sacc[mtk][ntq][r] = -1e30f;
                    }
                    pw[mtk][ntq].x = pk2(__builtin_amdgcn_exp2f(sacc[mtk][ntq][0] - M8L2E_),
                                         __builtin_amdgcn_exp2f(sacc[mtk][ntq][1] - M8L2E_));
                    pw[mtk][ntq].y = pk2(__builtin_amdgcn_exp2f(sacc[mtk][ntq][2] - M8L2E_),
                                         __builtin_amdgcn_exp2f(sacc[mtk][ntq][3] - M8L2E_));
                }
            // O += P V ; l += P * ones  -- key-block-paired x32 MFMAs, operands all in registers
            #pragma unroll
            for (int pr = 0; pr < 2; pr++) {
                int ma = pr * 2, mb = pr * 2 + 1;
                bf16x8 ap[2];
                #pragma unroll
                for (int ntq = 0; ntq < 2; ntq++) ap[ntq] = cat8(pw[ma][ntq], pw[mb][ntq]);
                #pragma unroll
                for (int ntd = 0; ntd < 4; ntd++) {
                    bf16x8 vb = cat8(vraw[ma][ntd], vraw[mb][ntd]);
                    #pragma unroll
                    for (int ntq = 0; ntq < 2; ntq++)
                        o[ntq][ntd] = __builtin_amdgcn_mfma_f32_16x16x32_bf16(ap[ntq], vb, o[ntq][ntd], 0, 0, 0);
                }
                #pragma unroll
                for (int ntq = 0; ntq < 2; ntq++)
                    lacc[ntq] = __builtin_amdgcn_mfma_f32_16x16x32_bf16(ap[ntq], ones, lacc[ntq], 0, 0, 0);
            }
        }

        // per-wave Obuf regions are disjoint: no barrier needed before writes
        #pragma unroll
        for (int mt = 0; mt < 2; mt++)
            #pragma unroll
            for (int nt = 0; nt < 4; nt++)
                #pragma unroll
                for (int r = 0; r < 4; r++)
                    Obuf[w * 2048 + (mt * 16 + quad * 4 + r) * 64 + nt * 16 + col] = o[mt][nt][r];
        if (col == 0) {
            #pragma unroll
            for (int mt = 0; mt < 2; mt++)
                #pragma unroll
                for (int r = 0; r < 4; r++)
                    lbuf[w][mt * 16 + quad * 4 + r] = lacc[mt][r];
        }
        __syncthreads();
        {
            int row = tid >> 3, d0 = (tid & 7) * 8;
            float ls = lbuf[0][row] + lbuf[1][row] + lbuf[2][row] + lbuf[3][row];
            float inv = 1.0f / ls;
            float s[8];
            #pragma unroll
            for (int j = 0; j < 8; j++) s[j] = 0.f;
            #pragma unroll
            for (int wv = 0; wv < 4; wv++) {
                f32x4 p0 = *(const f32x4*)&Obuf[wv * 2048 + row * 64 + d0];
                f32x4 p1 = *(const f32x4*)&Obuf[wv * 2048 + row * 64 + d0 + 4];
                #pragma unroll
                for (int j = 0; j < 4; j++) { s[j] += p0[j]; s[4 + j] += p1[j]; }
            }
            unsigned short o8[8];
            #pragma unroll
            for (int j = 0; j < 8; j++) o8[j] = f2bf(s[j] * inv);
            *(uint4*)&yb[(size_t)(b * T_ + t0 + row) * C_ + h * 64 + d0] = *(uint4*)o8;
        }
        __syncthreads();   // merge reads done before next tile reuses Obuf
    }
}

// ---------------------------------------------------------------- launch
extern "C" void kernel_launch(void* const* d_in, const int* in_sizes, int n_in,
                              void* d_out, int out_size, void* d_ws, size_t ws_size,
                              hipStream_t stream) {
    const float* x    = (const float*)d_in[0];
    const float* cosb = (const float*)d_in[1];
    const float* sinb = (const float*)d_in[2];
    const float* Wq   = (const float*)d_in[3];
    const float* Wk   = (const float*)d_in[4];
    const float* Wv   = (const float*)d_in[5];
    const float* Wo   = (const float*)d_in[6];
    float* out = (float*)d_out;

    char* ws = (char*)d_ws;
    unsigned short* xb    = (unsigned short*)(ws);               // 8 MB (reused as yb)
    unsigned short* yb    = (unsigned short*)(ws);               // alias: xb dead after QKV GEMM
    unsigned short* wtqkv = (unsigned short*)(ws + ( 8u << 20)); // 3 MB
    unsigned short* wto   = (unsigned short*)(ws + (11u << 20)); // 2 MB
    unsigned short* qkvb  = (unsigned short*)(ws + (13u << 20)); // 12 MB (v region unused)
    unsigned short* vtb   = (unsigned short*)(ws + (25u << 20)); // 2 MB

    prep_kernel<<<4096 + 2560, 256, 0, stream>>>(x, xb, Wq, Wk, Wv, Wo, wtqkv, wto);
    // QKV projection + fused RoPE/RMSNorm (q,k) + fused V-transpose (v -> vtb)
    gemm_kernel<unsigned short, true><<<dim3(24, 32), 256, 0, stream>>>(xb, wtqkv, qkvb, NQKV_, cosb, sinb, vtb);
    // split-K flash attention, balanced qt-pairing, all-register P (no LDS round-trip)
    attn_kernel<<<1024, 256, 0, stream>>>(qkvb, vtb, yb);
    // output projection -> fp32 out
    gemm_kernel<float, false><<<dim3(16, 32), 256, 0, stream>>>(yb, wto, out, C_, nullptr, nullptr, nullptr);
}

// Round 4
// 202.446 us; speedup vs baseline: 1.0773x; 1.0773x over previous
//
#include <hip/hip_runtime.h>
#include <hip/hip_bf16.h>

#define B_   2
#define T_   2048
#define C_   1024
#define H_   16
#define KV_  4
#define HD_  64
#define M_   (B_*T_)     // 4096 tokens
#define NQKV_ 1536       // 1024 q + 256 k + 256 v (v region unused now)
#define PST_ 72          // P LDS row stride (bf16): 144 B
#define M8L2E_ 11.5415603f   // 8 * log2(e)

typedef __bf16 bf16x8 __attribute__((ext_vector_type(8)));
typedef float  f32x4  __attribute__((ext_vector_type(4)));

static __device__ __forceinline__ unsigned short f2bf(float f) {
    __hip_bfloat16 h = __float2bfloat16(f);
    return __builtin_bit_cast(unsigned short, h);
}
static __device__ __forceinline__ unsigned int pk2(float a, float b) {
    return (unsigned int)f2bf(a) | ((unsigned int)f2bf(b) << 16);
}

// ---------------------------------------------------------------- prep: cast x + 4 weight transposes
__global__ void prep_kernel(const float* __restrict__ x, unsigned short* __restrict__ xb,
                            const float* __restrict__ Wq, const float* __restrict__ Wk,
                            const float* __restrict__ Wv, const float* __restrict__ Wo,
                            unsigned short* __restrict__ wtqkv, unsigned short* __restrict__ wto) {
    __shared__ float tile[32][33];
    int bid = blockIdx.x;
    if (bid < 4096) {   // cast x -> bf16
        int i = (bid * 256 + threadIdx.x) * 4;
        float4 v = *(const float4*)(x + i);
        ushort4 o = make_ushort4(f2bf(v.x), f2bf(v.y), f2bf(v.z), f2bf(v.w));
        *(ushort4*)(xb + i) = o;
        return;
    }
    bid -= 4096;
    const float* src; unsigned short* dst; int s, nlog;
    if (bid < 1024)      { src = Wq; dst = wtqkv;               s = bid;        nlog = 5; }
    else if (bid < 1280) { src = Wk; dst = wtqkv + 1024 * 1024; s = bid - 1024; nlog = 3; }
    else if (bid < 1536) { src = Wv; dst = wtqkv + 1280 * 1024; s = bid - 1280; nlog = 3; }
    else                 { src = Wo; dst = wto;                 s = bid - 1536; nlog = 5; }
    int N  = 32 << nlog;
    int k0 = (s >> nlog) * 32, n0 = (s & ((1 << nlog) - 1)) * 32;
    int lr = threadIdx.x >> 5, lc = threadIdx.x & 31;
    #pragma unroll
    for (int i = 0; i < 4; i++) {
        int r = lr + i * 8;
        tile[r][lc] = src[(k0 + r) * N + n0 + lc];
    }
    __syncthreads();
    #pragma unroll
    for (int i = 0; i < 4; i++) {
        int r = lr + i * 8;
        dst[(n0 + r) * 1024 + k0 + lc] = f2bf(tile[lc][r]);
    }
}

// ------------------------------------------------ 128x128 bf16 MFMA GEMM, K=1024, BK=64
// m93/m97 structure: 256 threads, 2x2 waves, 64x64 per wave (4x4 frags), 2-barrier loop,
// global_load_lds x16B staging. grid = (n-blocks, m-blocks), x fastest -> same-A-panel
// blocks temporally adjacent (L2-hot).
// ROPE=true: head = 2*blockIdx.x + wc (heads are 64-wide; q|k|v boundaries at 16/20 are
// even so a wave never mixes head types). heads 0..15 q (RoPE+RMS, *0.125*log2e),
// 16..19 k (RoPE+RMS), 20..23 v -> written TRANSPOSED to vtb[(b*KV+kvh)*64+d][t].
template <typename T, bool ROPE>
__global__ __launch_bounds__(256) void gemm_kernel(const unsigned short* __restrict__ A,
                                                   const unsigned short* __restrict__ Bt,
                                                   T* __restrict__ Cm, int Ni,
                                                   const float* __restrict__ cosb,
                                                   const float* __restrict__ sinb,
                                                   unsigned short* __restrict__ vtb) {
    __shared__ __align__(16) unsigned short As[2][128 * 32];
    __shared__ __align__(16) unsigned short Bs[2][128 * 32];
    int n0 = blockIdx.x * 128;
    int m0 = blockIdx.y * 128;
    int tid = threadIdx.x;
    int w = tid >> 6, lane = tid & 63;
    int col = lane & 15, quad = lane >> 4;
    int wr = (w >> 1) * 64, wc = (w & 1) * 64;   // wave tile origin inside block
    int ar = tid >> 2, ak = (tid & 3) * 8;       // staging: row 0..63, 8-elem chunk

    f32x4 acc[4][4];
    #pragma unroll
    for (int mt = 0; mt < 4; mt++)
        #pragma unroll
        for (int nt = 0; nt < 4; nt++) acc[mt][nt] = (f32x4){0.f, 0.f, 0.f, 0.f};

    for (int k0 = 0; k0 < 1024; k0 += 64) {
        #pragma unroll
        for (int hh = 0; hh < 2; hh++) {
            __builtin_amdgcn_global_load_lds(
                (const __attribute__((address_space(1))) unsigned int*)(A + (size_t)(m0 + ar) * 1024 + k0 + hh * 32 + ak),
                (__attribute__((address_space(3))) unsigned int*)(&As[hh][ar * 32 + ak]), 16, 0, 0);
            __builtin_amdgcn_global_load_lds(
                (const __attribute__((address_space(1))) unsigned int*)(A + (size_t)(m0 + ar + 64) * 1024 + k0 + hh * 32 + ak),
                (__attribute__((address_space(3))) unsigned int*)(&As[hh][(ar + 64) * 32 + ak]), 16, 0, 0);
            __builtin_amdgcn_global_load_lds(
                (const __attribute__((address_space(1))) unsigned int*)(Bt + (size_t)(n0 + ar) * 1024 + k0 + hh * 32 + ak),
                (__attribute__((address_space(3))) unsigned int*)(&Bs[hh][ar * 32 + ak]), 16, 0, 0);
            __builtin_amdgcn_global_load_lds(
                (const __attribute__((address_space(1))) unsigned int*)(Bt + (size_t)(n0 + ar + 64) * 1024 + k0 + hh * 32 + ak),
                (__attribute__((address_space(3))) unsigned int*)(&Bs[hh][(ar + 64) * 32 + ak]), 16, 0, 0);
        }
        __syncthreads();
        bf16x8 af[4][2], bfr[4][2];
        #pragma unroll
        for (int hh = 0; hh < 2; hh++) {
            #pragma unroll
            for (int mt = 0; mt < 4; mt++) af[mt][hh]  = *(const bf16x8*)&As[hh][(wr + mt * 16 + col) * 32 + quad * 8];
            #pragma unroll
            for (int nt = 0; nt < 4; nt++) bfr[nt][hh] = *(const bf16x8*)&Bs[hh][(wc + nt * 16 + col) * 32 + quad * 8];
        }
        #pragma unroll
        for (int hh = 0; hh < 2; hh++)
            #pragma unroll
            for (int mt = 0; mt < 4; mt++)
                #pragma unroll
                for (int nt = 0; nt < 4; nt++)
                    acc[mt][nt] = __builtin_amdgcn_mfma_f32_16x16x32_bf16(af[mt][hh], bfr[nt][hh], acc[mt][nt], 0, 0, 0);
        __syncthreads();
    }

    if constexpr (ROPE) {
        int head = blockIdx.x * 2 + (w & 1);
        if (head >= H_ + KV_) {
            // v head: write transposed to vtb[(b*KV+kvh)*64 + d][t], packed 4x bf16 (t-contig)
            int kvh = head - (H_ + KV_);
            int b = m0 >> 11;
            #pragma unroll
            for (int mt = 0; mt < 4; mt++) {
                int tb = (m0 + wr + mt * 16 + quad * 4) & (T_ - 1);
                #pragma unroll
                for (int nt = 0; nt < 4; nt++) {
                    int d = nt * 16 + col;
                    uint2 pv;
                    pv.x = pk2(acc[mt][nt][0], acc[mt][nt][1]);
                    pv.y = pk2(acc[mt][nt][2], acc[mt][nt][3]);
                    *(uint2*)&vtb[((size_t)((b * KV_ + kvh) * 64 + d)) * T_ + tb] = pv;
                }
            }
            return;
        }
        // q/k head: RoPE + RMSNorm (head dims live in this wave's 64-wide column slice)
        #pragma unroll
        for (int mt = 0; mt < 4; mt++)
            #pragma unroll
            for (int r = 0; r < 4; r++) {
                int t = (m0 + wr + mt * 16 + quad * 4 + r) & (T_ - 1);
                float nv[4];
                #pragma unroll
                for (int nt = 0; nt < 4; nt++) {
                    int i = (nt & 1) * 16 + col;
                    float c = cosb[t * 32 + i], s = sinb[t * 32 + i];
                    float v = acc[mt][nt][r], p = acc[mt][nt ^ 2][r];
                    nv[nt] = (nt < 2) ? (v * c + p * s) : (v * c - p * s);
                }
                float sq = nv[0] * nv[0] + nv[1] * nv[1] + nv[2] * nv[2] + nv[3] * nv[3];
                sq += __shfl_xor(sq, 1, 64);
                sq += __shfl_xor(sq, 2, 64);
                sq += __shfl_xor(sq, 4, 64);
                sq += __shfl_xor(sq, 8, 64);
                float rr = rsqrtf(sq * (1.0f / 64.0f) + 1e-6f);
                if (head < H_) rr *= 0.125f * 1.44269504f;   // attn scale * log2(e) folded into q
                #pragma unroll
                for (int nt = 0; nt < 4; nt++) acc[mt][nt][r] = nv[nt] * rr;
            }
    }

    #pragma unroll
    for (int mt = 0; mt < 4; mt++)
        #pragma unroll
        for (int nt = 0; nt < 4; nt++)
            #pragma unroll
            for (int r = 0; r < 4; r++) {
                size_t idx = (size_t)(m0 + wr + mt * 16 + quad * 4 + r) * Ni + n0 + wc + nt * 16 + col;
                if constexpr (sizeof(T) == 2) Cm[idx] = f2bf(acc[mt][nt][r]);
                else                          Cm[idx] = acc[mt][nt][r];
            }
}

// ------------------------------------------------ MFMA flash attention: split-K, S^T trick
// (round-2 version, 74us proven; the all-register-PV rewrite regressed to 102us: 16x b64 V
// loads doubled VMEM request count and the LDS round-trip was never on the critical path.)
// BALANCED PAIRING: nkt(qt) + nkt(63-qt) == 33 for every qt -> block handles q-tile pair
// (63-pi, pi): 1024 identical blocks, all co-resident, zero tail, zero imbalance.
// NOTE: plain __launch_bounds__(256). min-waves=4 once forced VGPR to 64 -> 95 MB spill. Never re-add.
// QK^T computed TRANSPOSED (A=K, B=Q) so each lane's 4 acc values have consecutive keys
// -> P written to LDS as 8 ds_write_b64. PV reads P q-major (b128).
// Fixed-max softmax via exp2 (log2e folded into q): p = 2^(s' - 8*log2e), additive partials.
__global__ __launch_bounds__(256) void attn_kernel(const unsigned short* __restrict__ qkvb,
                                                   const unsigned short* __restrict__ vtb,
                                                   unsigned short* __restrict__ yb) {
    __shared__ __align__(16) char smem[4 * 32 * 64 * 4];   // 32 KB: P stripes (loop) / Obuf fp32 (merge)
    __shared__ float lbuf[4][32];

    int bh = blockIdx.x & 31;
    int pi = blockIdx.x >> 5;               // pair index 0..31
    int b = bh >> 4, h = bh & 15, kvh = h >> 2;
    int tid = threadIdx.x;
    int w = tid >> 6, lane = tid & 63;
    int col = lane & 15, quad = lane >> 4;

    unsigned short* Ps = (unsigned short*)smem + w * (32 * PST_);
    float* Obuf = (float*)smem;

    const unsigned short* kptr = qkvb + (size_t)(b * T_) * NQKV_ + 1024 + kvh * 64;
    const unsigned short* vptr = vtb + (size_t)((b * KV_ + kvh) * 64) * T_;

    bf16x8 ones;
    #pragma unroll
    for (int j = 0; j < 8; j++) ones[j] = (__bf16)1.0f;

    for (int ti = 0; ti < 2; ti++) {
        int qt = ti ? pi : 63 - pi;         // big tile first
        int t0 = qt * 32;
        int nkt = (t0 + 95) >> 6;           // 64-key tiles covering keys <= t0+31
        int we = ti ? 3 - w : w;            // reversed wave order on 2nd tile

        // Q B-frags (loop-invariant per tile): lane(col=q, quad) holds Q[t0+ntq*16+col][quad*8+step*32..]
        bf16x8 aq[2][2];
        #pragma unroll
        for (int ntq = 0; ntq < 2; ntq++)
            #pragma unroll
            for (int step = 0; step < 2; step++)
                aq[ntq][step] = *(const bf16x8*)&qkvb[(size_t)(b * T_ + t0 + ntq * 16 + col) * NQKV_
                                                      + h * 64 + quad * 8 + step * 32];

        f32x4 o[2][4], lacc[2];
        #pragma unroll
        for (int mt = 0; mt < 2; mt++) {
            lacc[mt] = (f32x4){0.f, 0.f, 0.f, 0.f};
            #pragma unroll
            for (int nt = 0; nt < 4; nt++) o[mt][nt] = (f32x4){0.f, 0.f, 0.f, 0.f};
        }

        for (int kt = we; kt < nkt; kt += 4) {
            // S^T = K Q^T : A-frag = K rows (key), B-frag = Q
            f32x4 sacc[4][2];
            #pragma unroll
            for (int mtk = 0; mtk < 4; mtk++)
                #pragma unroll
                for (int ntq = 0; ntq < 2; ntq++) sacc[mtk][ntq] = (f32x4){0.f, 0.f, 0.f, 0.f};
            #pragma unroll
            for (int step = 0; step < 2; step++) {
                bf16x8 kb[4];
                #pragma unroll
                for (int mtk = 0; mtk < 4; mtk++)
                    kb[mtk] = *(const bf16x8*)&kptr[(size_t)(kt * 64 + mtk * 16 + col) * NQKV_
                                                    + quad * 8 + step * 32];
                #pragma unroll
                for (int mtk = 0; mtk < 4; mtk++)
                    #pragma unroll
                    for (int ntq = 0; ntq < 2; ntq++)
                        sacc[mtk][ntq] = __builtin_amdgcn_mfma_f32_16x16x32_bf16(kb[mtk], aq[ntq][step], sacc[mtk][ntq], 0, 0, 0);
            }
            // issue V loads; latency hides under exp/pack
            bf16x8 vb[2][4];
            #pragma unroll
            for (int step = 0; step < 2; step++)
                #pragma unroll
                for (int ntd = 0; ntd < 4; ntd++)
                    vb[step][ntd] = *(const bf16x8*)&vptr[(size_t)(ntd * 16 + col) * T_
                                                          + kt * 64 + quad * 8 + step * 32];
            if (kt == nkt - 1) {   // diagonal: causal mask (S^T indices: row=key, col=q)
                #pragma unroll
                for (int mtk = 0; mtk < 4; mtk++)
                    #pragma unroll
                    for (int ntq = 0; ntq < 2; ntq++)
                        #pragma unroll
                        for (int r = 0; r < 4; r++)
                            if (kt * 64 + mtk * 16 + quad * 4 + r > t0 + ntq * 16 + col)
                                sacc[mtk][ntq][r] = -1e30f;
            }
            // p = 2^(s' - 8*log2e); lane's 4 values are key-consecutive -> one b64 write each
            // raw v_exp_f32 (no OCML denorm wrapper): these sit on the serial chain
            #pragma unroll
            for (int mtk = 0; mtk < 4; mtk++)
                #pragma unroll
                for (int ntq = 0; ntq < 2; ntq++) {
                    uint2 pw;
                    pw.x = pk2(__builtin_amdgcn_exp2f(sacc[mtk][ntq][0] - M8L2E_),
                               __builtin_amdgcn_exp2f(sacc[mtk][ntq][1] - M8L2E_));
                    pw.y = pk2(__builtin_amdgcn_exp2f(sacc[mtk][ntq][2] - M8L2E_),
                               __builtin_amdgcn_exp2f(sacc[mtk][ntq][3] - M8L2E_));
                    *(uint2*)&Ps[(ntq * 16 + col) * PST_ + mtk * 16 + quad * 4] = pw;
                }
            // O += P V ; l += P * ones  (P read q-major as A-frag, b128)
            #pragma unroll
            for (int step = 0; step < 2; step++) {
                bf16x8 ap[2];
                #pragma unroll
                for (int mtq = 0; mtq < 2; mtq++)
                    ap[mtq] = *(const bf16x8*)&Ps[(mtq * 16 + col) * PST_ + quad * 8 + step * 32];
                #pragma unroll
                for (int ntd = 0; ntd < 4; ntd++)
                    #pragma unroll
                    for (int mtq = 0; mtq < 2; mtq++)
                        o[mtq][ntd] = __builtin_amdgcn_mfma_f32_16x16x32_bf16(ap[mtq], vb[step][ntd], o[mtq][ntd], 0, 0, 0);
                #pragma unroll
                for (int mtq = 0; mtq < 2; mtq++)
                    lacc[mtq] = __builtin_amdgcn_mfma_f32_16x16x32_bf16(ap[mtq], ones, lacc[mtq], 0, 0, 0);
            }
        }

        __syncthreads();   // all waves done with P space
        #pragma unroll
        for (int mt = 0; mt < 2; mt++)
            #pragma unroll
            for (int nt = 0; nt < 4; nt++)
                #pragma unroll
                for (int r = 0; r < 4; r++)
                    Obuf[w * 2048 + (mt * 16 + quad * 4 + r) * 64 + nt * 16 + col] = o[mt][nt][r];
        if (col == 0) {
            #pragma unroll
            for (int mt = 0; mt < 2; mt++)
                #pragma unroll
                for (int r = 0; r < 4; r++)
                    lbuf[w][mt * 16 + quad * 4 + r] = lacc[mt][r];
        }
        __syncthreads();
        {
            int row = tid >> 3, d0 = (tid & 7) * 8;
            float ls = lbuf[0][row] + lbuf[1][row] + lbuf[2][row] + lbuf[3][row];
            float inv = 1.0f / ls;
            float s[8];
            #pragma unroll
            for (int j = 0; j < 8; j++) s[j] = 0.f;
            #pragma unroll
            for (int wv = 0; wv < 4; wv++) {
                f32x4 p0 = *(const f32x4*)&Obuf[wv * 2048 + row * 64 + d0];
                f32x4 p1 = *(const f32x4*)&Obuf[wv * 2048 + row * 64 + d0 + 4];
                #pragma unroll
                for (int j = 0; j < 4; j++) { s[j] += p0[j]; s[4 + j] += p1[j]; }
            }
            unsigned short o8[8];
            #pragma unroll
            for (int j = 0; j < 8; j++) o8[j] = f2bf(s[j] * inv);
            *(uint4*)&yb[(size_t)(b * T_ + t0 + row) * C_ + h * 64 + d0] = *(uint4*)o8;
        }
        __syncthreads();   // merge reads done before next tile reuses Obuf
    }
}

// ---------------------------------------------------------------- launch
extern "C" void kernel_launch(void* const* d_in, const int* in_sizes, int n_in,
                              void* d_out, int out_size, void* d_ws, size_t ws_size,
                              hipStream_t stream) {
    const float* x    = (const float*)d_in[0];
    const float* cosb = (const float*)d_in[1];
    const float* sinb = (const float*)d_in[2];
    const float* Wq   = (const float*)d_in[3];
    const float* Wk   = (const float*)d_in[4];
    const float* Wv   = (const float*)d_in[5];
    const float* Wo   = (const float*)d_in[6];
    float* out = (float*)d_out;

    char* ws = (char*)d_ws;
    unsigned short* xb    = (unsigned short*)(ws);               // 8 MB (reused as yb)
    unsigned short* yb    = (unsigned short*)(ws);               // alias: xb dead after QKV GEMM
    unsigned short* wtqkv = (unsigned short*)(ws + ( 8u << 20)); // 3 MB
    unsigned short* wto   = (unsigned short*)(ws + (11u << 20)); // 2 MB
    unsigned short* qkvb  = (unsigned short*)(ws + (13u << 20)); // 12 MB (v region unused)
    unsigned short* vtb   = (unsigned short*)(ws + (25u << 20)); // 2 MB

    prep_kernel<<<4096 + 2560, 256, 0, stream>>>(x, xb, Wq, Wk, Wv, Wo, wtqkv, wto);
    // QKV projection + fused RoPE/RMSNorm (q,k) + fused V-transpose (v -> vtb), 128x128 tiles
    gemm_kernel<unsigned short, true><<<dim3(12, 32), 256, 0, stream>>>(xb, wtqkv, qkvb, NQKV_, cosb, sinb, vtb);
    // split-K flash attention, balanced qt-pairing (round-2 proven version)
    attn_kernel<<<1024, 256, 0, stream>>>(qkvb, vtb, yb);
    // output projection -> fp32 out, 128x128 tiles
    gemm_kernel<float, false><<<dim3(8, 32), 256, 0, stream>>>(yb, wto, out, C_, nullptr, nullptr, nullptr);
}

// Round 5
// 167.003 us; speedup vs baseline: 1.3059x; 1.2122x over previous
//
#include <hip/hip_runtime.h>
#include <hip/hip_bf16.h>

#define B_   2
#define T_   2048
#define C_   1024
#define H_   16
#define KV_  4
#define HD_  64
#define M_   (B_*T_)     // 4096 tokens
#define QSTR_ 1024       // qkvb row stride: Q only (k/v redirected to ktb/vfb)
#define PST_ 72          // P LDS row stride (bf16): 144 B
#define M8L2E_ 11.5415603f   // 8 * log2(e)

typedef __bf16 bf16x8 __attribute__((ext_vector_type(8)));
typedef float  f32x4  __attribute__((ext_vector_type(4)));

static __device__ __forceinline__ unsigned short f2bf(float f) {
    __hip_bfloat16 h = __float2bfloat16(f);
    return __builtin_bit_cast(unsigned short, h);
}
static __device__ __forceinline__ unsigned int pk2(float a, float b) {
    return (unsigned int)f2bf(a) | ((unsigned int)f2bf(b) << 16);
}

// ---------------------------------------------------------------- prep: cast x + 4 weight transposes
__global__ void prep_kernel(const float* __restrict__ x, unsigned short* __restrict__ xb,
                            const float* __restrict__ Wq, const float* __restrict__ Wk,
                            const float* __restrict__ Wv, const float* __restrict__ Wo,
                            unsigned short* __restrict__ wtqkv, unsigned short* __restrict__ wto) {
    __shared__ float tile[32][33];
    int bid = blockIdx.x;
    if (bid < 4096) {   // cast x -> bf16
        int i = (bid * 256 + threadIdx.x) * 4;
        float4 v = *(const float4*)(x + i);
        ushort4 o = make_ushort4(f2bf(v.x), f2bf(v.y), f2bf(v.z), f2bf(v.w));
        *(ushort4*)(xb + i) = o;
        return;
    }
    bid -= 4096;
    const float* src; unsigned short* dst; int s, nlog;
    if (bid < 1024)      { src = Wq; dst = wtqkv;               s = bid;        nlog = 5; }
    else if (bid < 1280) { src = Wk; dst = wtqkv + 1024 * 1024; s = bid - 1024; nlog = 3; }
    else if (bid < 1536) { src = Wv; dst = wtqkv + 1280 * 1024; s = bid - 1280; nlog = 3; }
    else                 { src = Wo; dst = wto;                 s = bid - 1536; nlog = 5; }
    int N  = 32 << nlog;
    int k0 = (s >> nlog) * 32, n0 = (s & ((1 << nlog) - 1)) * 32;
    int lr = threadIdx.x >> 5, lc = threadIdx.x & 31;
    #pragma unroll
    for (int i = 0; i < 4; i++) {
        int r = lr + i * 8;
        tile[r][lc] = src[(k0 + r) * N + n0 + lc];
    }
    __syncthreads();
    #pragma unroll
    for (int i = 0; i < 4; i++) {
        int r = lr + i * 8;
        dst[(n0 + r) * 1024 + k0 + lc] = f2bf(tile[lc][r]);
    }
}

// ------------------------------------------------ 128x64 bf16 MFMA GEMM, K=1024, BK=64
// grid = (heads, m-blocks): head-major so same-A-panel blocks are temporally adjacent (L2-hot).
// ROPE=true: heads 0..15 q (RoPE+RMS, *0.125*log2e) -> qkvb (stride 1024);
//   16..19 k (RoPE+RMS) -> ktb in MFMA-FRAGMENT ORDER:
//        elem(t,d) at (t>>4)*1024 + (d>>5)*512 + (t&15)*32 + (d&31)
//   20..23 v -> vfb in fragment order: ((t>>5)*4 + (d>>4))*512 + (d&15)*32 + (t&31)
// so attn's K/V fragment loads are single CONTIGUOUS 1KB wave loads (4 coalesced
// transactions) instead of 16-cache-line gathers (the round<=4 74us attn wall:
// ~4cyc/line-touch of L1 transaction throughput, measured via the r3 b64-V regression).
template <typename T, bool ROPE>
__global__ __launch_bounds__(256) void gemm_kernel(const unsigned short* __restrict__ A,
                                                   const unsigned short* __restrict__ Bt,
                                                   T* __restrict__ Cm, int Ni,
                                                   const float* __restrict__ cosb,
                                                   const float* __restrict__ sinb,
                                                   unsigned short* __restrict__ vfb,
                                                   unsigned short* __restrict__ ktb) {
    __shared__ __align__(16) unsigned short As[2][128 * 32];
    __shared__ __align__(16) unsigned short Bs[2][64 * 32];
    int head = blockIdx.x;
    int m0 = blockIdx.y * 128;
    int n0 = head * 64;
    int tid = threadIdx.x;
    int w = tid >> 6, lane = tid & 63;
    int col = lane & 15, quad = lane >> 4;
    int wm = w * 32;
    int ar = tid >> 2, ak = (tid & 3) * 8;

    f32x4 acc[2][4];
    #pragma unroll
    for (int mt = 0; mt < 2; mt++)
        #pragma unroll
        for (int nt = 0; nt < 4; nt++) acc[mt][nt] = (f32x4){0.f, 0.f, 0.f, 0.f};

    for (int k0 = 0; k0 < 1024; k0 += 64) {
        #pragma unroll
        for (int hh = 0; hh < 2; hh++) {
            __builtin_amdgcn_global_load_lds(
                (const __attribute__((address_space(1))) unsigned int*)(A + (size_t)(m0 + ar) * 1024 + k0 + hh * 32 + ak),
                (__attribute__((address_space(3))) unsigned int*)(&As[hh][ar * 32 + ak]), 16, 0, 0);
            __builtin_amdgcn_global_load_lds(
                (const __attribute__((address_space(1))) unsigned int*)(A + (size_t)(m0 + ar + 64) * 1024 + k0 + hh * 32 + ak),
                (__attribute__((address_space(3))) unsigned int*)(&As[hh][(ar + 64) * 32 + ak]), 16, 0, 0);
            __builtin_amdgcn_global_load_lds(
                (const __attribute__((address_space(1))) unsigned int*)(Bt + (size_t)(n0 + ar) * 1024 + k0 + hh * 32 + ak),
                (__attribute__((address_space(3))) unsigned int*)(&Bs[hh][ar * 32 + ak]), 16, 0, 0);
        }
        __syncthreads();
        bf16x8 af[2][2], bfr[4][2];
        #pragma unroll
        for (int hh = 0; hh < 2; hh++) {
            #pragma unroll
            for (int mt = 0; mt < 2; mt++) af[mt][hh]  = *(const bf16x8*)&As[hh][(wm + mt * 16 + col) * 32 + quad * 8];
            #pragma unroll
            for (int nt = 0; nt < 4; nt++) bfr[nt][hh] = *(const bf16x8*)&Bs[hh][(nt * 16 + col) * 32 + quad * 8];
        }
        #pragma unroll
        for (int hh = 0; hh < 2; hh++)
            #pragma unroll
            for (int mt = 0; mt < 2; mt++)
                #pragma unroll
                for (int nt = 0; nt < 4; nt++)
                    acc[mt][nt] = __builtin_amdgcn_mfma_f32_16x16x32_bf16(af[mt][hh], bfr[nt][hh], acc[mt][nt], 0, 0, 0);
        __syncthreads();
    }

    if constexpr (ROPE) {
        int b = m0 >> 11;
        if (head >= H_ + KV_) {
            // v head: fragment-ordered vfb write, uint2 (4 consecutive t at fixed d)
            int kvh = head - (H_ + KV_);
            unsigned short* vbase = vfb + (size_t)(b * KV_ + kvh) * (T_ * 64);
            #pragma unroll
            for (int mt = 0; mt < 2; mt++) {
                int tb = (m0 + wm + mt * 16 + quad * 4) & (T_ - 1);
                #pragma unroll
                for (int nt = 0; nt < 4; nt++) {
                    uint2 pv;
                    pv.x = pk2(acc[mt][nt][0], acc[mt][nt][1]);
                    pv.y = pk2(acc[mt][nt][2], acc[mt][nt][3]);
                    *(uint2*)&vbase[((tb >> 5) * 4 + nt) * 512 + col * 32 + (tb & 31)] = pv;
                }
            }
            return;
        }
        // q/k head: RoPE + RMSNorm
        #pragma unroll
        for (int mt = 0; mt < 2; mt++)
            #pragma unroll
            for (int r = 0; r < 4; r++) {
                int t = (m0 + wm + mt * 16 + quad * 4 + r) & (T_ - 1);
                float nv[4];
                #pragma unroll
                for (int nt = 0; nt < 4; nt++) {
                    int i = (nt & 1) * 16 + col;
                    float c = cosb[t * 32 + i], s = sinb[t * 32 + i];
                    float v = acc[mt][nt][r], p = acc[mt][nt ^ 2][r];
                    nv[nt] = (nt < 2) ? (v * c + p * s) : (v * c - p * s);
                }
                float sq = nv[0] * nv[0] + nv[1] * nv[1] + nv[2] * nv[2] + nv[3] * nv[3];
                sq += __shfl_xor(sq, 1, 64);
                sq += __shfl_xor(sq, 2, 64);
                sq += __shfl_xor(sq, 4, 64);
                sq += __shfl_xor(sq, 8, 64);
                float rr = rsqrtf(sq * (1.0f / 64.0f) + 1e-6f);
                if (head < H_) rr *= 0.125f * 1.44269504f;   // attn scale * log2(e) folded into q
                #pragma unroll
                for (int nt = 0; nt < 4; nt++) acc[mt][nt][r] = nv[nt] * rr;
            }
        if (head >= H_) {
            // k head: fragment-ordered ktb write (elementwise, same count as old C-write)
            int kvh = head - H_;
            unsigned short* kbase = ktb + (size_t)(b * KV_ + kvh) * (T_ * 64);
            #pragma unroll
            for (int mt = 0; mt < 2; mt++)
                #pragma unroll
                for (int r = 0; r < 4; r++) {
                    int t = (m0 + wm + mt * 16 + quad * 4 + r) & (T_ - 1);
                    #pragma unroll
                    for (int nt = 0; nt < 4; nt++) {
                        int dd = nt * 16 + col;
                        kbase[(t >> 4) * 1024 + (dd >> 5) * 512 + (t & 15) * 32 + (dd & 31)] = f2bf(acc[mt][nt][r]);
                    }
                }
            return;
        }
    }

    #pragma unroll
    for (int mt = 0; mt < 2; mt++)
        #pragma unroll
        for (int nt = 0; nt < 4; nt++)
            #pragma unroll
            for (int r = 0; r < 4; r++) {
                size_t idx = (size_t)(m0 + wm + mt * 16 + quad * 4 + r) * Ni + n0 + nt * 16 + col;
                if constexpr (sizeof(T) == 2) Cm[idx] = f2bf(acc[mt][nt][r]);
                else                          Cm[idx] = acc[mt][nt][r];
            }
}

// ------------------------------------------------ MFMA flash attention: split-K, S^T trick
// (round-2 proven structure; only the K/V load ADDRESSES change: fragment-ordered ktb/vfb
// make every fragment load one contiguous 1KB wave load -> 4 coalesced 256B transactions
// instead of a 16-cache-line gather. K/V VMEM transactions drop 4x.)
// BALANCED PAIRING: nkt(qt)+nkt(63-qt)==33 -> block handles pair (63-pi, pi): 1024
// identical blocks, all co-resident, zero tail, zero imbalance.
// NOTE: plain __launch_bounds__(256). min-waves=4 once forced VGPR to 64 -> 95 MB spill. Never re-add.
// QK^T computed TRANSPOSED (A=K, B=Q) so each lane's 4 acc values have consecutive keys
// -> P written to LDS as 8 ds_write_b64. PV reads P q-major (b128). (All-register PV
// regressed r3: the LDS round-trip is NOT on the critical path.)
// Fixed-max softmax via exp2 (log2e folded into q): p = 2^(s' - 8*log2e), additive partials.
__global__ __launch_bounds__(256) void attn_kernel(const unsigned short* __restrict__ qkvb,
                                                   const unsigned short* __restrict__ ktb,
                                                   const unsigned short* __restrict__ vfb,
                                                   unsigned short* __restrict__ yb) {
    __shared__ __align__(16) char smem[4 * 32 * 64 * 4];   // 32 KB: P stripes (loop) / Obuf fp32 (merge)
    __shared__ float lbuf[4][32];

    int bh = blockIdx.x & 31;
    int pi = blockIdx.x >> 5;               // pair index 0..31
    int b = bh >> 4, h = bh & 15, kvh = h >> 2;
    int tid = threadIdx.x;
    int w = tid >> 6, lane = tid & 63;
    int col = lane & 15, quad = lane >> 4;

    unsigned short* Ps = (unsigned short*)smem + w * (32 * PST_);
    float* Obuf = (float*)smem;

    const unsigned short* kfb = ktb + (size_t)(b * KV_ + kvh) * (T_ * 64);
    const unsigned short* vfp = vfb + (size_t)(b * KV_ + kvh) * (T_ * 64);

    bf16x8 ones;
    #pragma unroll
    for (int j = 0; j < 8; j++) ones[j] = (__bf16)1.0f;

    for (int ti = 0; ti < 2; ti++) {
        int qt = ti ? pi : 63 - pi;         // big tile first
        int t0 = qt * 32;
        int nkt = (t0 + 95) >> 6;           // 64-key tiles covering keys <= t0+31
        int we = ti ? 3 - w : w;            // reversed wave order on 2nd tile

        // Q B-frags (loop-invariant per tile): lane(col=q, quad) holds Q[t0+ntq*16+col][quad*8+step*32..]
        bf16x8 aq[2][2];
        #pragma unroll
        for (int ntq = 0; ntq < 2; ntq++)
            #pragma unroll
            for (int step = 0; step < 2; step++)
                aq[ntq][step] = *(const bf16x8*)&qkvb[(size_t)(b * T_ + t0 + ntq * 16 + col) * QSTR_
                                                      + h * 64 + quad * 8 + step * 32];

        f32x4 o[2][4], lacc[2];
        #pragma unroll
        for (int mt = 0; mt < 2; mt++) {
            lacc[mt] = (f32x4){0.f, 0.f, 0.f, 0.f};
            #pragma unroll
            for (int nt = 0; nt < 4; nt++) o[mt][nt] = (f32x4){0.f, 0.f, 0.f, 0.f};
        }

        for (int kt = we; kt < nkt; kt += 4) {
            // S^T = K Q^T : A-frag = K rows (key), B-frag = Q
            // kb load: one contiguous 1KB wave load from fragment-ordered ktb
            f32x4 sacc[4][2];
            #pragma unroll
            for (int mtk = 0; mtk < 4; mtk++)
                #pragma unroll
                for (int ntq = 0; ntq < 2; ntq++) sacc[mtk][ntq] = (f32x4){0.f, 0.f, 0.f, 0.f};
            #pragma unroll
            for (int step = 0; step < 2; step++) {
                bf16x8 kb[4];
                #pragma unroll
                for (int mtk = 0; mtk < 4; mtk++)
                    kb[mtk] = *(const bf16x8*)&kfb[(kt * 4 + mtk) * 1024 + step * 512 + col * 32 + quad * 8];
                #pragma unroll
                for (int mtk = 0; mtk < 4; mtk++)
                    #pragma unroll
                    for (int ntq = 0; ntq < 2; ntq++)
                        sacc[mtk][ntq] = __builtin_amdgcn_mfma_f32_16x16x32_bf16(kb[mtk], aq[ntq][step], sacc[mtk][ntq], 0, 0, 0);
            }
            // issue V loads (contiguous 1KB each); latency hides under exp/pack
            bf16x8 vb[2][4];
            #pragma unroll
            for (int step = 0; step < 2; step++)
                #pragma unroll
                for (int ntd = 0; ntd < 4; ntd++)
                    vb[step][ntd] = *(const bf16x8*)&vfp[((kt * 2 + step) * 4 + ntd) * 512 + col * 32 + quad * 8];
            if (kt == nkt - 1) {   // diagonal: causal mask (S^T indices: row=key, col=q)
                #pragma unroll
                for (int mtk = 0; mtk < 4; mtk++)
                    #pragma unroll
                    for (int ntq = 0; ntq < 2; ntq++)
                        #pragma unroll
                        for (int r = 0; r < 4; r++)
                            if (kt * 64 + mtk * 16 + quad * 4 + r > t0 + ntq * 16 + col)
                                sacc[mtk][ntq][r] = -1e30f;
            }
            // p = 2^(s' - 8*log2e); lane's 4 values are key-consecutive -> one b64 write each
            #pragma unroll
            for (int mtk = 0; mtk < 4; mtk++)
                #pragma unroll
                for (int ntq = 0; ntq < 2; ntq++) {
                    uint2 pw;
                    pw.x = pk2(__builtin_amdgcn_exp2f(sacc[mtk][ntq][0] - M8L2E_),
                               __builtin_amdgcn_exp2f(sacc[mtk][ntq][1] - M8L2E_));
                    pw.y = pk2(__builtin_amdgcn_exp2f(sacc[mtk][ntq][2] - M8L2E_),
                               __builtin_amdgcn_exp2f(sacc[mtk][ntq][3] - M8L2E_));
                    *(uint2*)&Ps[(ntq * 16 + col) * PST_ + mtk * 16 + quad * 4] = pw;
                }
            // O += P V ; l += P * ones  (P read q-major as A-frag, b128)
            #pragma unroll
            for (int step = 0; step < 2; step++) {
                bf16x8 ap[2];
                #pragma unroll
                for (int mtq = 0; mtq < 2; mtq++)
                    ap[mtq] = *(const bf16x8*)&Ps[(mtq * 16 + col) * PST_ + quad * 8 + step * 32];
                #pragma unroll
                for (int ntd = 0; ntd < 4; ntd++)
                    #pragma unroll
                    for (int mtq = 0; mtq < 2; mtq++)
                        o[mtq][ntd] = __builtin_amdgcn_mfma_f32_16x16x32_bf16(ap[mtq], vb[step][ntd], o[mtq][ntd], 0, 0, 0);
                #pragma unroll
                for (int mtq = 0; mtq < 2; mtq++)
                    lacc[mtq] = __builtin_amdgcn_mfma_f32_16x16x32_bf16(ap[mtq], ones, lacc[mtq], 0, 0, 0);
            }
        }

        __syncthreads();   // all waves done with P space
        #pragma unroll
        for (int mt = 0; mt < 2; mt++)
            #pragma unroll
            for (int nt = 0; nt < 4; nt++)
                #pragma unroll
                for (int r = 0; r < 4; r++)
                    Obuf[w * 2048 + (mt * 16 + quad * 4 + r) * 64 + nt * 16 + col] = o[mt][nt][r];
        if (col == 0) {
            #pragma unroll
            for (int mt = 0; mt < 2; mt++)
                #pragma unroll
                for (int r = 0; r < 4; r++)
                    lbuf[w][mt * 16 + quad * 4 + r] = lacc[mt][r];
        }
        __syncthreads();
        {
            int row = tid >> 3, d0 = (tid & 7) * 8;
            float ls = lbuf[0][row] + lbuf[1][row] + lbuf[2][row] + lbuf[3][row];
            float inv = 1.0f / ls;
            float s[8];
            #pragma unroll
            for (int j = 0; j < 8; j++) s[j] = 0.f;
            #pragma unroll
            for (int wv = 0; wv < 4; wv++) {
                f32x4 p0 = *(const f32x4*)&Obuf[wv * 2048 + row * 64 + d0];
                f32x4 p1 = *(const f32x4*)&Obuf[wv * 2048 + row * 64 + d0 + 4];
                #pragma unroll
                for (int j = 0; j < 4; j++) { s[j] += p0[j]; s[4 + j] += p1[j]; }
            }
            unsigned short o8[8];
            #pragma unroll
            for (int j = 0; j < 8; j++) o8[j] = f2bf(s[j] * inv);
            *(uint4*)&yb[(size_t)(b * T_ + t0 + row) * C_ + h * 64 + d0] = *(uint4*)o8;
        }
        __syncthreads();   // merge reads done before next tile reuses Obuf
    }
}

// ---------------------------------------------------------------- launch
extern "C" void kernel_launch(void* const* d_in, const int* in_sizes, int n_in,
                              void* d_out, int out_size, void* d_ws, size_t ws_size,
                              hipStream_t stream) {
    const float* x    = (const float*)d_in[0];
    const float* cosb = (const float*)d_in[1];
    const float* sinb = (const float*)d_in[2];
    const float* Wq   = (const float*)d_in[3];
    const float* Wk   = (const float*)d_in[4];
    const float* Wv   = (const float*)d_in[5];
    const float* Wo   = (const float*)d_in[6];
    float* out = (float*)d_out;

    char* ws = (char*)d_ws;
    unsigned short* xb    = (unsigned short*)(ws);               // 8 MB (reused as yb)
    unsigned short* yb    = (unsigned short*)(ws);               // alias: xb dead after QKV GEMM
    unsigned short* wtqkv = (unsigned short*)(ws + ( 8u << 20)); // 3 MB
    unsigned short* wto   = (unsigned short*)(ws + (11u << 20)); // 2 MB
    unsigned short* qkvb  = (unsigned short*)(ws + (13u << 20)); // 8 MB (Q only, stride 1024)
    unsigned short* vfb   = (unsigned short*)(ws + (21u << 20)); // 2 MB fragment-ordered V
    unsigned short* ktb   = (unsigned short*)(ws + (23u << 20)); // 2 MB fragment-ordered K

    prep_kernel<<<4096 + 2560, 256, 0, stream>>>(x, xb, Wq, Wk, Wv, Wo, wtqkv, wto);
    // QKV projection + fused RoPE/RMSNorm; q -> qkvb, k -> ktb (frag order), v -> vfb (frag order)
    gemm_kernel<unsigned short, true><<<dim3(24, 32), 256, 0, stream>>>(xb, wtqkv, qkvb, QSTR_, cosb, sinb, vfb, ktb);
    // split-K flash attention, balanced qt-pairing, coalesced fragment loads
    attn_kernel<<<1024, 256, 0, stream>>>(qkvb, ktb, vfb, yb);
    // output projection -> fp32 out
    gemm_kernel<float, false><<<dim3(16, 32), 256, 0, stream>>>(yb, wto, out, C_, nullptr, nullptr, nullptr, nullptr);
}

// Round 7
// 163.339 us; speedup vs baseline: 1.3352x; 1.0224x over previous
//
#include <hip/hip_runtime.h>
#include <hip/hip_bf16.h>

#define B_   2
#define T_   2048
#define C_   1024
#define H_   16
#define KV_  4
#define HD_  64
#define M_   (B_*T_)     // 4096 tokens
#define QSTR_ 1024       // qkvb row stride: Q only (k/v redirected to ktb/vfb)
#define PST_ 72          // P LDS row stride (bf16): 144 B
#define M8L2E_ 11.5415603f   // 8 * log2(e)

typedef __bf16 bf16x8 __attribute__((ext_vector_type(8)));
typedef float  f32x4  __attribute__((ext_vector_type(4)));

static __device__ __forceinline__ unsigned short f2bf(float f) {
    __hip_bfloat16 h = __float2bfloat16(f);
    return __builtin_bit_cast(unsigned short, h);
}
static __device__ __forceinline__ unsigned int pk2(float a, float b) {
    return (unsigned int)f2bf(a) | ((unsigned int)f2bf(b) << 16);
}
// NOTE (r6 failure): v_cvt_pk_bf16_f32 inline asm as "lo=src0,hi=src1" produced absmax 1.83
// (vs 0.0078 with pk2) — operand-order/semantics assumption wrong on this toolchain.
// Keep the RNE scalar pack; do NOT reintroduce the asm without an isolated refcheck.

// ---------------------------------------------------------------- prep: cast x + 4 weight transposes
__global__ void prep_kernel(const float* __restrict__ x, unsigned short* __restrict__ xb,
                            const float* __restrict__ Wq, const float* __restrict__ Wk,
                            const float* __restrict__ Wv, const float* __restrict__ Wo,
                            unsigned short* __restrict__ wtqkv, unsigned short* __restrict__ wto) {
    __shared__ float tile[32][33];
    int bid = blockIdx.x;
    if (bid < 4096) {   // cast x -> bf16
        int i = (bid * 256 + threadIdx.x) * 4;
        float4 v = *(const float4*)(x + i);
        ushort4 o = make_ushort4(f2bf(v.x), f2bf(v.y), f2bf(v.z), f2bf(v.w));
        *(ushort4*)(xb + i) = o;
        return;
    }
    bid -= 4096;
    const float* src; unsigned short* dst; int s, nlog;
    if (bid < 1024)      { src = Wq; dst = wtqkv;               s = bid;        nlog = 5; }
    else if (bid < 1280) { src = Wk; dst = wtqkv + 1024 * 1024; s = bid - 1024; nlog = 3; }
    else if (bid < 1536) { src = Wv; dst = wtqkv + 1280 * 1024; s = bid - 1280; nlog = 3; }
    else                 { src = Wo; dst = wto;                 s = bid - 1536; nlog = 5; }
    int N  = 32 << nlog;
    int k0 = (s >> nlog) * 32, n0 = (s & ((1 << nlog) - 1)) * 32;
    int lr = threadIdx.x >> 5, lc = threadIdx.x & 31;
    #pragma unroll
    for (int i = 0; i < 4; i++) {
        int r = lr + i * 8;
        tile[r][lc] = src[(k0 + r) * N + n0 + lc];
    }
    __syncthreads();
    #pragma unroll
    for (int i = 0; i < 4; i++) {
        int r = lr + i * 8;
        dst[(n0 + r) * 1024 + k0 + lc] = f2bf(tile[lc][r]);
    }
}

// ------------------------------------------------ 128x64 bf16 MFMA GEMM, K=1024, BK=64
// 1D grid with BIJECTIVE XCD-CHUNK SWIZZLE (T1), m-major within XCD: XCD x gets swz in
// [x*NH*4, (x+1)*NH*4) = 4 m-blocks x all NH heads. Per-XCD working set = A(1MB)+B(3MB)
// = L2-sized; each 256KB A panel fetched by exactly ONE XCD (was: head-fastest dispatch
// round-robins same-A blocks across all 8 XCDs -> ~88MB L2-miss traffic vs 32MB minimum).
// ROPE=true: heads 0..15 q (RoPE+RMS, *0.125*log2e) -> qkvb (stride 1024);
//   16..19 k (RoPE+RMS) -> ktb in MFMA-FRAGMENT ORDER:
//        elem(t,d) at (t>>4)*1024 + (d>>5)*512 + (t&15)*32 + (d&31)
//   20..23 v -> vfb in fragment order: ((t>>5)*4 + (d>>4))*512 + (d&15)*32 + (t&31)
// so attn's K/V fragment loads are single CONTIGUOUS 1KB wave loads (r5: attn 73->49us).
template <typename T, bool ROPE, int NH>
__global__ __launch_bounds__(256) void gemm_kernel(const unsigned short* __restrict__ A,
                                                   const unsigned short* __restrict__ Bt,
                                                   T* __restrict__ Cm, int Ni,
                                                   const float* __restrict__ cosb,
                                                   const float* __restrict__ sinb,
                                                   unsigned short* __restrict__ vfb,
                                                   unsigned short* __restrict__ ktb) {
    __shared__ __align__(16) unsigned short As[2][128 * 32];
    __shared__ __align__(16) unsigned short Bs[2][64 * 32];
    int bid = blockIdx.x;
    int swz = (bid & 7) * (NH * 4) + (bid >> 3);   // nwg = NH*32, divisible by 8
    int head = swz % NH;
    int m0 = (swz / NH) * 128;
    int n0 = head * 64;
    int tid = threadIdx.x;
    int w = tid >> 6, lane = tid & 63;
    int col = lane & 15, quad = lane >> 4;
    int wm = w * 32;
    int ar = tid >> 2, ak = (tid & 3) * 8;

    f32x4 acc[2][4];
    #pragma unroll
    for (int mt = 0; mt < 2; mt++)
        #pragma unroll
        for (int nt = 0; nt < 4; nt++) acc[mt][nt] = (f32x4){0.f, 0.f, 0.f, 0.f};

    for (int k0 = 0; k0 < 1024; k0 += 64) {
        #pragma unroll
        for (int hh = 0; hh < 2; hh++) {
            __builtin_amdgcn_global_load_lds(
                (const __attribute__((address_space(1))) unsigned int*)(A + (size_t)(m0 + ar) * 1024 + k0 + hh * 32 + ak),
                (__attribute__((address_space(3))) unsigned int*)(&As[hh][ar * 32 + ak]), 16, 0, 0);
            __builtin_amdgcn_global_load_lds(
                (const __attribute__((address_space(1))) unsigned int*)(A + (size_t)(m0 + ar + 64) * 1024 + k0 + hh * 32 + ak),
                (__attribute__((address_space(3))) unsigned int*)(&As[hh][(ar + 64) * 32 + ak]), 16, 0, 0);
            __builtin_amdgcn_global_load_lds(
                (const __attribute__((address_space(1))) unsigned int*)(Bt + (size_t)(n0 + ar) * 1024 + k0 + hh * 32 + ak),
                (__attribute__((address_space(3))) unsigned int*)(&Bs[hh][ar * 32 + ak]), 16, 0, 0);
        }
        __syncthreads();
        bf16x8 af[2][2], bfr[4][2];
        #pragma unroll
        for (int hh = 0; hh < 2; hh++) {
            #pragma unroll
            for (int mt = 0; mt < 2; mt++) af[mt][hh]  = *(const bf16x8*)&As[hh][(wm + mt * 16 + col) * 32 + quad * 8];
            #pragma unroll
            for (int nt = 0; nt < 4; nt++) bfr[nt][hh] = *(const bf16x8*)&Bs[hh][(nt * 16 + col) * 32 + quad * 8];
        }
        #pragma unroll
        for (int hh = 0; hh < 2; hh++)
            #pragma unroll
            for (int mt = 0; mt < 2; mt++)
                #pragma unroll
                for (int nt = 0; nt < 4; nt++)
                    acc[mt][nt] = __builtin_amdgcn_mfma_f32_16x16x32_bf16(af[mt][hh], bfr[nt][hh], acc[mt][nt], 0, 0, 0);
        __syncthreads();
    }

    if constexpr (ROPE) {
        int b = m0 >> 11;
        if (head >= H_ + KV_) {
            // v head: fragment-ordered vfb write, uint2 (4 consecutive t at fixed d)
            int kvh = head - (H_ + KV_);
            unsigned short* vbase = vfb + (size_t)(b * KV_ + kvh) * (T_ * 64);
            #pragma unroll
            for (int mt = 0; mt < 2; mt++) {
                int tb = (m0 + wm + mt * 16 + quad * 4) & (T_ - 1);
                #pragma unroll
                for (int nt = 0; nt < 4; nt++) {
                    uint2 pv;
                    pv.x = pk2(acc[mt][nt][0], acc[mt][nt][1]);
                    pv.y = pk2(acc[mt][nt][2], acc[mt][nt][3]);
                    *(uint2*)&vbase[((tb >> 5) * 4 + nt) * 512 + col * 32 + (tb & 31)] = pv;
                }
            }
            return;
        }
        // q/k head: RoPE + RMSNorm
        #pragma unroll
        for (int mt = 0; mt < 2; mt++)
            #pragma unroll
            for (int r = 0; r < 4; r++) {
                int t = (m0 + wm + mt * 16 + quad * 4 + r) & (T_ - 1);
                float nv[4];
                #pragma unroll
                for (int nt = 0; nt < 4; nt++) {
                    int i = (nt & 1) * 16 + col;
                    float c = cosb[t * 32 + i], s = sinb[t * 32 + i];
                    float v = acc[mt][nt][r], p = acc[mt][nt ^ 2][r];
                    nv[nt] = (nt < 2) ? (v * c + p * s) : (v * c - p * s);
                }
                float sq = nv[0] * nv[0] + nv[1] * nv[1] + nv[2] * nv[2] + nv[3] * nv[3];
                sq += __shfl_xor(sq, 1, 64);
                sq += __shfl_xor(sq, 2, 64);
                sq += __shfl_xor(sq, 4, 64);
                sq += __shfl_xor(sq, 8, 64);
                float rr = rsqrtf(sq * (1.0f / 64.0f) + 1e-6f);
                if (head < H_) rr *= 0.125f * 1.44269504f;   // attn scale * log2(e) folded into q
                #pragma unroll
                for (int nt = 0; nt < 4; nt++) acc[mt][nt][r] = nv[nt] * rr;
            }
        if (head >= H_) {
            // k head: fragment-ordered ktb write (elementwise, same count as old C-write)
            int kvh = head - H_;
            unsigned short* kbase = ktb + (size_t)(b * KV_ + kvh) * (T_ * 64);
            #pragma unroll
            for (int mt = 0; mt < 2; mt++)
                #pragma unroll
                for (int r = 0; r < 4; r++) {
                    int t = (m0 + wm + mt * 16 + quad * 4 + r) & (T_ - 1);
                    #pragma unroll
                    for (int nt = 0; nt < 4; nt++) {
                        int dd = nt * 16 + col;
                        kbase[(t >> 4) * 1024 + (dd >> 5) * 512 + (t & 15) * 32 + (dd & 31)] = f2bf(acc[mt][nt][r]);
                    }
                }
            return;
        }
    }

    #pragma unroll
    for (int mt = 0; mt < 2; mt++)
        #pragma unroll
        for (int nt = 0; nt < 4; nt++)
            #pragma unroll
            for (int r = 0; r < 4; r++) {
                size_t idx = (size_t)(m0 + wm + mt * 16 + quad * 4 + r) * Ni + n0 + nt * 16 + col;
                if constexpr (sizeof(T) == 2) Cm[idx] = f2bf(acc[mt][nt][r]);
                else                          Cm[idx] = acc[mt][nt][r];
            }
}

// ------------------------------------------------ MFMA flash attention: split-K, S^T trick
// r5 proven structure (48.6us): fragment-ordered ktb/vfb -> every K/V fragment load is one
// contiguous 1KB wave load (4 coalesced transactions, not a 16-line gather).
// BALANCED PAIRING: nkt(qt)+nkt(63-qt)==33 -> block handles pair (63-pi, pi): 1024
// identical blocks, all co-resident, zero tail, zero imbalance.
// NOTE: plain __launch_bounds__(256). min-waves=4 once forced VGPR to 64 -> 95 MB spill. Never re-add.
// QK^T computed TRANSPOSED (A=K, B=Q) so each lane's 4 acc values have consecutive keys
// -> P written to LDS as 8 ds_write_b64. PV reads P q-major (b128). (All-register PV
// regressed r3: the LDS round-trip is NOT on the critical path.)
// Fixed-max softmax via exp2 (log2e folded into q): p = 2^(s' - 8*log2e), additive partials.
__global__ __launch_bounds__(256) void attn_kernel(const unsigned short* __restrict__ qkvb,
                                                   const unsigned short* __restrict__ ktb,
                                                   const unsigned short* __restrict__ vfb,
                                                   unsigned short* __restrict__ yb) {
    __shared__ __align__(16) char smem[4 * 32 * 64 * 4];   // 32 KB: P stripes (loop) / Obuf fp32 (merge)
    __shared__ float lbuf[4][32];

    int bh = blockIdx.x & 31;
    int pi = blockIdx.x >> 5;               // pair index 0..31
    int b = bh >> 4, h = bh & 15, kvh = h >> 2;
    int tid = threadIdx.x;
    int w = tid >> 6, lane = tid & 63;
    int col = lane & 15, quad = lane >> 4;

    unsigned short* Ps = (unsigned short*)smem + w * (32 * PST_);
    float* Obuf = (float*)smem;

    const unsigned short* kfb = ktb + (size_t)(b * KV_ + kvh) * (T_ * 64);
    const unsigned short* vfp = vfb + (size_t)(b * KV_ + kvh) * (T_ * 64);

    bf16x8 ones;
    #pragma unroll
    for (int j = 0; j < 8; j++) ones[j] = (__bf16)1.0f;

    for (int ti = 0; ti < 2; ti++) {
        int qt = ti ? pi : 63 - pi;         // big tile first
        int t0 = qt * 32;
        int nkt = (t0 + 95) >> 6;           // 64-key tiles covering keys <= t0+31
        int we = ti ? 3 - w : w;            // reversed wave order on 2nd tile

        // Q B-frags (loop-invariant per tile): lane(col=q, quad) holds Q[t0+ntq*16+col][quad*8+step*32..]
        bf16x8 aq[2][2];
        #pragma unroll
        for (int ntq = 0; ntq < 2; ntq++)
            #pragma unroll
            for (int step = 0; step < 2; step++)
                aq[ntq][step] = *(const bf16x8*)&qkvb[(size_t)(b * T_ + t0 + ntq * 16 + col) * QSTR_
                                                      + h * 64 + quad * 8 + step * 32];

        f32x4 o[2][4], lacc[2];
        #pragma unroll
        for (int mt = 0; mt < 2; mt++) {
            lacc[mt] = (f32x4){0.f, 0.f, 0.f, 0.f};
            #pragma unroll
            for (int nt = 0; nt < 4; nt++) o[mt][nt] = (f32x4){0.f, 0.f, 0.f, 0.f};
        }

        for (int kt = we; kt < nkt; kt += 4) {
            // S^T = K Q^T : A-frag = K rows (key), B-frag = Q
            // kb load: one contiguous 1KB wave load from fragment-ordered ktb
            f32x4 sacc[4][2];
            #pragma unroll
            for (int mtk = 0; mtk < 4; mtk++)
                #pragma unroll
                for (int ntq = 0; ntq < 2; ntq++) sacc[mtk][ntq] = (f32x4){0.f, 0.f, 0.f, 0.f};
            #pragma unroll
            for (int step = 0; step < 2; step++) {
                bf16x8 kb[4];
                #pragma unroll
                for (int mtk = 0; mtk < 4; mtk++)
                    kb[mtk] = *(const bf16x8*)&kfb[(kt * 4 + mtk) * 1024 + step * 512 + col * 32 + quad * 8];
                #pragma unroll
                for (int mtk = 0; mtk < 4; mtk++)
                    #pragma unroll
                    for (int ntq = 0; ntq < 2; ntq++)
                        sacc[mtk][ntq] = __builtin_amdgcn_mfma_f32_16x16x32_bf16(kb[mtk], aq[ntq][step], sacc[mtk][ntq], 0, 0, 0);
            }
            // issue V loads (contiguous 1KB each); latency hides under exp/pack
            bf16x8 vb[2][4];
            #pragma unroll
            for (int step = 0; step < 2; step++)
                #pragma unroll
                for (int ntd = 0; ntd < 4; ntd++)
                    vb[step][ntd] = *(const bf16x8*)&vfp[((kt * 2 + step) * 4 + ntd) * 512 + col * 32 + quad * 8];
            if (kt == nkt - 1) {   // diagonal: causal mask (S^T indices: row=key, col=q)
                #pragma unroll
                for (int mtk = 0; mtk < 4; mtk++)
                    #pragma unroll
                    for (int ntq = 0; ntq < 2; ntq++)
                        #pragma unroll
                        for (int r = 0; r < 4; r++)
                            if (kt * 64 + mtk * 16 + quad * 4 + r > t0 + ntq * 16 + col)
                                sacc[mtk][ntq][r] = -1e30f;
            }
            // p = 2^(s' - 8*log2e); lane's 4 values are key-consecutive -> one b64 write each
            #pragma unroll
            for (int mtk = 0; mtk < 4; mtk++)
                #pragma unroll
                for (int ntq = 0; ntq < 2; ntq++) {
                    uint2 pw;
                    pw.x = pk2(__builtin_amdgcn_exp2f(sacc[mtk][ntq][0] - M8L2E_),
                               __builtin_amdgcn_exp2f(sacc[mtk][ntq][1] - M8L2E_));
                    pw.y = pk2(__builtin_amdgcn_exp2f(sacc[mtk][ntq][2] - M8L2E_),
                               __builtin_amdgcn_exp2f(sacc[mtk][ntq][3] - M8L2E_));
                    *(uint2*)&Ps[(ntq * 16 + col) * PST_ + mtk * 16 + quad * 4] = pw;
                }
            // O += P V ; l += P * ones  (P read q-major as A-frag, b128)
            #pragma unroll
            for (int step = 0; step < 2; step++) {
                bf16x8 ap[2];
                #pragma unroll
                for (int mtq = 0; mtq < 2; mtq++)
                    ap[mtq] = *(const bf16x8*)&Ps[(mtq * 16 + col) * PST_ + quad * 8 + step * 32];
                #pragma unroll
                for (int ntd = 0; ntd < 4; ntd++)
                    #pragma unroll
                    for (int mtq = 0; mtq < 2; mtq++)
                        o[mtq][ntd] = __builtin_amdgcn_mfma_f32_16x16x32_bf16(ap[mtq], vb[step][ntd], o[mtq][ntd], 0, 0, 0);
                #pragma unroll
                for (int mtq = 0; mtq < 2; mtq++)
                    lacc[mtq] = __builtin_amdgcn_mfma_f32_16x16x32_bf16(ap[mtq], ones, lacc[mtq], 0, 0, 0);
            }
        }

        __syncthreads();   // all waves done with P space
        #pragma unroll
        for (int mt = 0; mt < 2; mt++)
            #pragma unroll
            for (int nt = 0; nt < 4; nt++)
                #pragma unroll
                for (int r = 0; r < 4; r++)
                    Obuf[w * 2048 + (mt * 16 + quad * 4 + r) * 64 + nt * 16 + col] = o[mt][nt][r];
        if (col == 0) {
            #pragma unroll
            for (int mt = 0; mt < 2; mt++)
                #pragma unroll
                for (int r = 0; r < 4; r++)
                    lbuf[w][mt * 16 + quad * 4 + r] = lacc[mt][r];
        }
        __syncthreads();
        {
            int row = tid >> 3, d0 = (tid & 7) * 8;
            float ls = lbuf[0][row] + lbuf[1][row] + lbuf[2][row] + lbuf[3][row];
            float inv = 1.0f / ls;
            float s[8];
            #pragma unroll
            for (int j = 0; j < 8; j++) s[j] = 0.f;
            #pragma unroll
            for (int wv = 0; wv < 4; wv++) {
                f32x4 p0 = *(const f32x4*)&Obuf[wv * 2048 + row * 64 + d0];
                f32x4 p1 = *(const f32x4*)&Obuf[wv * 2048 + row * 64 + d0 + 4];
                #pragma unroll
                for (int j = 0; j < 4; j++) { s[j] += p0[j]; s[4 + j] += p1[j]; }
            }
            unsigned short o8[8];
            #pragma unroll
            for (int j = 0; j < 8; j++) o8[j] = f2bf(s[j] * inv);
            *(uint4*)&yb[(size_t)(b * T_ + t0 + row) * C_ + h * 64 + d0] = *(uint4*)o8;
        }
        __syncthreads();   // merge reads done before next tile reuses Obuf
    }
}

// ---------------------------------------------------------------- launch
extern "C" void kernel_launch(void* const* d_in, const int* in_sizes, int n_in,
                              void* d_out, int out_size, void* d_ws, size_t ws_size,
                              hipStream_t stream) {
    const float* x    = (const float*)d_in[0];
    const float* cosb = (const float*)d_in[1];
    const float* sinb = (const float*)d_in[2];
    const float* Wq   = (const float*)d_in[3];
    const float* Wk   = (const float*)d_in[4];
    const float* Wv   = (const float*)d_in[5];
    const float* Wo   = (const float*)d_in[6];
    float* out = (float*)d_out;

    char* ws = (char*)d_ws;
    unsigned short* xb    = (unsigned short*)(ws);               // 8 MB (reused as yb)
    unsigned short* yb    = (unsigned short*)(ws);               // alias: xb dead after QKV GEMM
    unsigned short* wtqkv = (unsigned short*)(ws + ( 8u << 20)); // 3 MB
    unsigned short* wto   = (unsigned short*)(ws + (11u << 20)); // 2 MB
    unsigned short* qkvb  = (unsigned short*)(ws + (13u << 20)); // 8 MB (Q only, stride 1024)
    unsigned short* vfb   = (unsigned short*)(ws + (21u << 20)); // 2 MB fragment-ordered V
    unsigned short* ktb   = (unsigned short*)(ws + (23u << 20)); // 2 MB fragment-ordered K

    prep_kernel<<<4096 + 2560, 256, 0, stream>>>(x, xb, Wq, Wk, Wv, Wo, wtqkv, wto);
    // QKV projection + fused RoPE/RMSNorm; q -> qkvb, k -> ktb (frag order), v -> vfb (frag order)
    // 1D grid 768 = 24 heads x 32 m-blocks, XCD-chunk swizzled (m-major per XCD)
    gemm_kernel<unsigned short, true, 24><<<768, 256, 0, stream>>>(xb, wtqkv, qkvb, QSTR_, cosb, sinb, vfb, ktb);
    // split-K flash attention, balanced qt-pairing, coalesced fragment loads
    attn_kernel<<<1024, 256, 0, stream>>>(qkvb, ktb, vfb, yb);
    // output projection -> fp32 out; 1D grid 512 = 16 x 32, XCD-chunk swizzled
    gemm_kernel<float, false, 16><<<512, 256, 0, stream>>>(yb, wto, out, C_, nullptr, nullptr, nullptr, nullptr);
}